// Round 8
// baseline (178.592 us; speedup 1.0000x reference)
//
#include <hip/hip_runtime.h>
#include <cstddef>
#include <cstdint>

namespace {
constexpr int kB   = 8;
constexpr int kT   = 2048;   // Tv == Ta
constexpr int kD   = 256;
constexpr int kK   = 8;      // num_neighbors (fixed by problem)
constexpr int kM   = kB * kT;
constexpr int kNCH = 64;     // s-chunks for gather partials
constexpr int kNC  = kB * kT;     // 16384 columns (b,s)
constexpr int kColCap = 64;       // bucket slots per column (mean load ~0.55)
constexpr int kOvCap  = 1 << 17;  // overflow list (normally empty)
constexpr float kMinNormalF = 1.17549435e-38f;  // 2^-126: fp32 exp flush boundary
}

typedef __attribute__((ext_vector_type(8)))  __bf16 bf16x8;
typedef __attribute__((ext_vector_type(16))) float  f32x16;

__device__ inline unsigned short f2bf_rne(float x) {
  unsigned u = __float_as_uint(x);
  unsigned r = (u + 0x7FFFu + ((u >> 16) & 1u)) >> 16;
  return (unsigned short)r;
}
__device__ inline float bf2f(unsigned short h) {
  return __uint_as_float((unsigned)h << 16);
}

// ---- Kernel 0: WT[c][k] = bf16(W[k][c]), both weights via blockIdx.z -------
__global__ __launch_bounds__(256) void transposeW2(const float* __restrict__ W0,
                                                   const float* __restrict__ W1,
                                                   unsigned short* __restrict__ T0,
                                                   unsigned short* __restrict__ T1) {
  const float* W = blockIdx.z ? W1 : W0;
  unsigned short* WT = blockIdx.z ? T1 : T0;
  __shared__ float tile[32][33];
  const int k0 = blockIdx.y * 32, c0 = blockIdx.x * 32;
  const int tx = threadIdx.x & 31, ty = threadIdx.x >> 5;  // 32 x 8
#pragma unroll
  for (int i = 0; i < 4; ++i)
    tile[ty + i * 8][tx] = W[(size_t)(k0 + ty + i * 8) * kD + c0 + tx];
  __syncthreads();
#pragma unroll
  for (int i = 0; i < 4; ++i)
    WT[(size_t)(c0 + ty + i * 8) * kD + k0 + tx] = f2bf_rne(tile[tx][ty + i * 8]);
}

// ---- Kernel 1: Cb = bf16( bf16(X) @ WT^T ) + fused row norms ---------------
// 64x128 block tile: X fp32 re-read 2x (was 4x at 64-wide N tiles). Direct
// staging (r6 lesson: register prefetch spills -> 251MB scratch traffic).
// Wave = 32 rows x 64 cols, acc[2], reads/MFMA = 1.5.
__global__ __launch_bounds__(256) void gemm_fused(const float* __restrict__ Xv,
                                                  const float* __restrict__ Xa,
                                                  const unsigned short* __restrict__ WvT,
                                                  const unsigned short* __restrict__ WaT,
                                                  unsigned short* __restrict__ Cv,
                                                  unsigned short* __restrict__ Ca,
                                                  float* __restrict__ nv,
                                                  float* __restrict__ na) {
  __shared__ unsigned short Xs[64 * 68];
  __shared__ unsigned short Ws[128 * 68];
  const int z = blockIdx.z;
  const float* X = z ? Xa : Xv;
  const unsigned short* WT = z ? WaT : WvT;
  unsigned short* Cb = z ? Ca : Cv;
  float* nrm = z ? na : nv;
  const int r0 = blockIdx.x * 64;
  const int c0 = blockIdx.y * 128;
  const int tid = threadIdx.x;
  const int wave = tid >> 6, lane = tid & 63;
  const int wt = wave & 1, wsi = wave >> 1;
  const int half = lane >> 5, ln = lane & 31;

  f32x16 acc[2];
#pragma unroll
  for (int j = 0; j < 2; ++j)
#pragma unroll
    for (int i = 0; i < 16; ++i) acc[j][i] = 0.0f;

  union Frag { uint2 u2[2]; bf16x8 v; };

  for (int k0 = 0; k0 < kD; k0 += 64) {
#pragma unroll
    for (int i = 0; i < 4; ++i) {       // X: 64 rows x 64 cols fp32, cast inline
      const int j = i * 256 + tid;
      const int row = j >> 4, c4 = (j & 15) * 4;
      const float4 v = *reinterpret_cast<const float4*>(X + (size_t)(r0 + row) * kD + k0 + c4);
      ushort4 o;
      o.x = f2bf_rne(v.x); o.y = f2bf_rne(v.y); o.z = f2bf_rne(v.z); o.w = f2bf_rne(v.w);
      *reinterpret_cast<ushort4*>(Xs + row * 68 + c4) = o;
    }
#pragma unroll
    for (int i = 0; i < 4; ++i) {       // WT: 128 rows x 64 shorts
      const int j = i * 256 + tid;
      const int row = j >> 3, c8 = (j & 7) * 8;
      const uint4 v = *reinterpret_cast<const uint4*>(WT + (size_t)(c0 + row) * kD + k0 + c8);
      *reinterpret_cast<uint4*>(Ws + row * 68 + c8) = v;
    }
    __syncthreads();
#pragma unroll
    for (int kk = 0; kk < 4; ++kk) {
      Frag fa, fb0, fb1;
      const uint2* pa = reinterpret_cast<const uint2*>(Xs + (wt * 32 + ln) * 68 + kk * 16 + half * 8);
      fa.u2[0] = pa[0]; fa.u2[1] = pa[1];
      const uint2* p0 = reinterpret_cast<const uint2*>(Ws + (wsi * 64 + ln) * 68 + kk * 16 + half * 8);
      fb0.u2[0] = p0[0]; fb0.u2[1] = p0[1];
      const uint2* p1 = reinterpret_cast<const uint2*>(Ws + (wsi * 64 + 32 + ln) * 68 + kk * 16 + half * 8);
      fb1.u2[0] = p1[0]; fb1.u2[1] = p1[1];
      acc[0] = __builtin_amdgcn_mfma_f32_32x32x16_bf16(fa.v, fb0.v, acc[0], 0, 0, 0);
      acc[1] = __builtin_amdgcn_mfma_f32_32x32x16_bf16(fa.v, fb1.v, acc[1], 0, 0, 0);
    }
    __syncthreads();
  }
  // epilogue: store bf16 C; accumulate row norms of the ROUNDED values
  float ns[16];
#pragma unroll
  for (int r = 0; r < 16; ++r) ns[r] = 0.0f;
#pragma unroll
  for (int jj = 0; jj < 2; ++jj) {
    const int col = c0 + wsi * 64 + jj * 32 + ln;
#pragma unroll
    for (int r = 0; r < 16; ++r) {
      const int row = r0 + wt * 32 + (r & 3) + 8 * (r >> 2) + 4 * half;
      const unsigned short us = f2bf_rne(acc[jj][r]);
      Cb[(size_t)row * kD + col] = us;
      const float f = bf2f(us);
      ns[r] += f * f;
    }
  }
#pragma unroll
  for (int r = 0; r < 16; ++r) {
    float v = ns[r];
#pragma unroll
    for (int off = 1; off < 32; off <<= 1) v += __shfl_xor(v, off, 64);
    if (ln == 0) {
      const int row = r0 + wt * 32 + (r & 3) + 8 * (r >> 2) + 4 * half;
      atomicAdd(nrm + row, v);
    }
  }
}

// ---- Kernel 2a: distance keys, 64(t) x 128(s) tile, direct staging ---------
// reads/MFMA 1.5 (was 2.0), 26.1KB LDS -> 6 blocks/CU, 4096 blocks. Epilogue
// guards on sq<7744 (== dist<88: sqrt monotone, sqrtf rounding can only
// produce dist==88 whose exp underflows anyway) so sqrt/exp run only for the
// ~3e-4 survivors. Selection semantics identical to rounds 1-7.
__global__ __launch_bounds__(256) void keys_mfma(const unsigned short* __restrict__ vmb,
                                                 const unsigned short* __restrict__ amb,
                                                 const float* __restrict__ vn2,
                                                 const float* __restrict__ an2,
                                                 unsigned* __restrict__ colCount,
                                                 uint2* __restrict__ colRecs,
                                                 unsigned* __restrict__ ovCount,
                                                 uint2* __restrict__ ovRecs) {
  __shared__ unsigned short vmS[64 * 68];
  __shared__ unsigned short amS[128 * 68];
  const int b = blockIdx.z;
  const int t0 = blockIdx.x * 64;
  const int s0 = blockIdx.y * 128;
  const int tid = threadIdx.x;
  const int wave = tid >> 6, lane = tid & 63;
  const int wt = wave & 1, wsi = wave >> 1;
  const int half = lane >> 5, ln = lane & 31;
  const unsigned short* vbase = vmb + ((size_t)b * kT + t0) * kD;
  const unsigned short* abase = amb + ((size_t)b * kT + s0) * kD;

  f32x16 acc[2];
#pragma unroll
  for (int j = 0; j < 2; ++j)
#pragma unroll
    for (int i = 0; i < 16; ++i) acc[j][i] = 0.0f;

  union Frag { uint2 u2[2]; bf16x8 v; };

  for (int k0 = 0; k0 < kD; k0 += 64) {
#pragma unroll
    for (int i = 0; i < 2; ++i) {       // vm: 64 rows x 64 shorts
      const int j = i * 256 + tid;
      const int row = j >> 3, c8 = (j & 7) * 8;
      const uint4 v = *reinterpret_cast<const uint4*>(vbase + (size_t)row * kD + k0 + c8);
      *reinterpret_cast<uint4*>(vmS + row * 68 + c8) = v;
    }
#pragma unroll
    for (int i = 0; i < 4; ++i) {       // am: 128 rows x 64 shorts
      const int j = i * 256 + tid;
      const int row = j >> 3, c8 = (j & 7) * 8;
      const uint4 a = *reinterpret_cast<const uint4*>(abase + (size_t)row * kD + k0 + c8);
      *reinterpret_cast<uint4*>(amS + row * 68 + c8) = a;
    }
    __syncthreads();
#pragma unroll
    for (int kk = 0; kk < 4; ++kk) {
      Frag fa, fb0, fb1;
      const uint2* pa = reinterpret_cast<const uint2*>(vmS + (wt * 32 + ln) * 68 + kk * 16 + half * 8);
      fa.u2[0] = pa[0]; fa.u2[1] = pa[1];
      const uint2* p0 = reinterpret_cast<const uint2*>(amS + (wsi * 64 + ln) * 68 + kk * 16 + half * 8);
      fb0.u2[0] = p0[0]; fb0.u2[1] = p0[1];
      const uint2* p1 = reinterpret_cast<const uint2*>(amS + (wsi * 64 + 32 + ln) * 68 + kk * 16 + half * 8);
      fb1.u2[0] = p1[0]; fb1.u2[1] = p1[1];
      acc[0] = __builtin_amdgcn_mfma_f32_32x32x16_bf16(fa.v, fb0.v, acc[0], 0, 0, 0);
      acc[1] = __builtin_amdgcn_mfma_f32_32x32x16_bf16(fa.v, fb1.v, acc[1], 0, 0, 0);
    }
    __syncthreads();
  }

  // epilogue: C/D layout col(s)=lane&31, row(t)=(reg&3)+8*(reg>>2)+4*half
  const float* v2p = vn2 + (size_t)b * kT + t0 + wt * 32;
#pragma unroll
  for (int j = 0; j < 2; ++j) {
    const int s = s0 + wsi * 64 + j * 32 + ln;
    const float a2 = an2[(size_t)b * kT + s];
    const int c = (b << 11) | s;
#pragma unroll
    for (int g = 0; g < 4; ++g) {
      const float4 v2 = *reinterpret_cast<const float4*>(v2p + g * 8 + half * 4);
      const float v2a[4] = {v2.x, v2.y, v2.z, v2.w};
#pragma unroll
      for (int q = 0; q < 4; ++q) {
        const float raw = v2a[q] + a2 - 2.0f * acc[j][4 * g + q];
        if (raw < 7744.0f) {  // == dist < 88; ~3e-4 of entries
          const float dist = sqrtf(fmaxf(raw, 0.0f));
          const float e = expf(-dist);
          if (e >= kMinNormalF) {
            const int t = t0 + wt * 32 + g * 8 + half * 4 + q;
            const unsigned slot = atomicAdd(&colCount[c], 1u);
            if (slot < (unsigned)kColCap) {
              colRecs[(size_t)c * kColCap + slot] = make_uint2(__float_as_uint(e), (unsigned)t);
            } else {
              const unsigned pos = ((unsigned)b << 22) | ((unsigned)s << 11) | (unsigned)t;
              const unsigned oi = atomicAdd(ovCount, 1u);
              if (oi < (unsigned)kOvCap) ovRecs[oi] = make_uint2(__float_as_uint(e), pos);
            }
          }
        }
      }
    }
  }
}

// ---- Kernel 2b: per-column top-8 from its own bucket -----------------------
// Writes idxT[(b*kK + r)*kT + s] (gather-friendly layout).
__global__ __launch_bounds__(256) void finalize_topk(const unsigned* __restrict__ colCount,
                                                     const uint2* __restrict__ colRecs,
                                                     const unsigned* __restrict__ ovCount,
                                                     const uint2* __restrict__ ovRecs,
                                                     int* __restrict__ idxT) {
  const int c = blockIdx.x * 256 + threadIdx.x;  // (b<<11)|s
  unsigned K[8];
  int T[8];
#pragma unroll
  for (int i = 0; i < 8; ++i) { K[i] = 0u; T[i] = 0x7FFFFFFF; }
  const int cnt = (int)colCount[c];
  const int m = min(cnt, kColCap);
  for (int i = 0; i < m; ++i) {
    const uint2 r = colRecs[(size_t)c * kColCap + i];
    const unsigned kx = r.x;
    const int tx = (int)r.y;
    if (kx > K[7] || (kx == K[7] && tx < T[7])) {
      K[7] = kx; T[7] = tx;
#pragma unroll
      for (int q = 7; q >= 1; --q) {
        const bool sw = (K[q] > K[q - 1]) || (K[q] == K[q - 1] && T[q] < T[q - 1]);
        if (sw) {
          const unsigned tk = K[q]; K[q] = K[q - 1]; K[q - 1] = tk;
          const int tt = T[q];      T[q] = T[q - 1]; T[q - 1] = tt;
        }
      }
    }
  }
  if (cnt > kColCap) {  // correctness fallback; normally never taken
    int n = (int)*ovCount;
    if (n > kOvCap) n = kOvCap;
    for (int i = 0; i < n; ++i) {
      const uint2 r = ovRecs[i];
      if ((int)(r.y >> 11) == c) {
        const unsigned kx = r.x;
        const int tx = (int)(r.y & 2047u);
        if (kx > K[7] || (kx == K[7] && tx < T[7])) {
          K[7] = kx; T[7] = tx;
#pragma unroll
          for (int q = 7; q >= 1; --q) {
            const bool sw = (K[q] > K[q - 1]) || (K[q] == K[q - 1] && T[q] < T[q - 1]);
            if (sw) {
              const unsigned tk = K[q]; K[q] = K[q - 1]; K[q - 1] = tk;
              const int tt = T[q];      T[q] = T[q - 1]; T[q - 1] = tt;
            }
          }
        }
      }
    }
  }
  int mcnt = 0;
#pragma unroll
  for (int i = 0; i < 8; ++i) if (K[i] > 0u) mcnt++;
  int outv[8];
#pragma unroll
  for (int i = 0; i < 8; ++i) outv[i] = T[i];
  int cand = 0;
  for (int r = mcnt; r < 8; ++r) {
    bool taken = true;
    while (taken) {
      taken = false;
#pragma unroll
      for (int q = 0; q < 8; ++q)
        if (q < mcnt && T[q] == cand) taken = true;
      if (taken) cand++;
    }
    outv[r] = cand++;
  }
  const int b = c >> 11, s = c & 2047;
#pragma unroll
  for (int r = 0; r < 8; ++r) idxT[((size_t)b * kK + r) * kT + s] = outv[r];
}

// ---- Kernel 3: gather-sums, atomicAdd straight into out (reduce fused) -----
__global__ __launch_bounds__(256) void gather_kernel(const float* __restrict__ visual,
                                                     const float* __restrict__ audio,
                                                     const int* __restrict__ idxT,
                                                     float* __restrict__ out) {
  const int blk = blockIdx.x;        // bj * kNCH + ch
  const int ch = blk & (kNCH - 1);
  const int bj = blk / kNCH;         // b*8 + j
  const int b = bj >> 3;
  const int d = threadIdx.x;
  const int* ip = idxT + (size_t)bj * kT + ch * (kT / kNCH);
  float accV = 0.f, accA = 0.f;
  for (int g = 0; g < kT / kNCH / 4; ++g) {
    const int4 cur = *reinterpret_cast<const int4*>(ip + g * 4);
    const int ts[4] = {cur.x, cur.y, cur.z, cur.w};
#pragma unroll
    for (int u = 0; u < 4; ++u) {
      const size_t base = ((size_t)b * kT + ts[u]) * kD + d;
      accV += visual[base];
      accA += audio[base];
    }
  }
  atomicAdd(out + (size_t)bj * kD + d, accV * (1.0f / kT));
  atomicAdd(out + (size_t)kB * kK * kD + (size_t)bj * kD + d, accA * (1.0f / kT));
}

extern "C" void kernel_launch(void* const* d_in, const int* in_sizes, int n_in,
                              void* d_out, int out_size, void* d_ws, size_t ws_size,
                              hipStream_t stream) {
  (void)in_sizes; (void)n_in; (void)ws_size;
  const float* visual = (const float*)d_in[0];
  const float* audio  = (const float*)d_in[1];
  const float* Wv     = (const float*)d_in[2];
  const float* Wa     = (const float*)d_in[3];
  float* out = (float*)d_out;

  // workspace layout (~27 MB). [vn2|an2|colCount|ovCount] contiguous: 1 memset.
  char* ws = (char*)d_ws;
  unsigned short* WvT = (unsigned short*)ws;                // kD*kD bf16 128KB
  unsigned short* WaT = WvT + (size_t)kD * kD;
  unsigned short* vmb = WaT + (size_t)kD * kD;              // kM*kD bf16  8MB
  unsigned short* amb = vmb + (size_t)kM * kD;              // 8MB
  float* vn2 = (float*)(amb + (size_t)kM * kD);             // kM f32 (memset)
  float* an2 = vn2 + kM;                                    // kM f32 (memset)
  unsigned* colCount = (unsigned*)(an2 + kM);               // kNC u32 (memset)
  unsigned* ovCount  = colCount + kNC;                      // 1 u32 +3 pad (memset)
  uint2* colRecs = (uint2*)(ovCount + 4);                   // kNC*kColCap uint2 8MB
  uint2* ovRecs  = colRecs + (size_t)kNC * kColCap;         // kOvCap uint2 1MB
  int* idxT = (int*)(ovRecs + kOvCap);                      // kB*kK*kT i32 512KB

  hipMemsetAsync(out, 0, (size_t)out_size * sizeof(float), stream);
  hipMemsetAsync(vn2, 0, (size_t)(2 * kM + kNC + 4) * sizeof(float), stream);
  transposeW2<<<dim3(kD / 32, kD / 32, 2), 256, 0, stream>>>(Wv, Wa, WvT, WaT);
  gemm_fused<<<dim3(kM / 64, kD / 128, 2), 256, 0, stream>>>(visual, audio, WvT, WaT,
                                                             vmb, amb, vn2, an2);
  keys_mfma<<<dim3(kT / 64, kT / 128, kB), 256, 0, stream>>>(vmb, amb, vn2, an2,
                                                             colCount, colRecs, ovCount, ovRecs);
  finalize_topk<<<dim3(kNC / 256), 256, 0, stream>>>(colCount, colRecs, ovCount, ovRecs, idxT);
  gather_kernel<<<dim3(kB * kK * kNCH), 256, 0, stream>>>(visual, audio, idxT, out);
}

// Round 9
// 173.788 us; speedup vs baseline: 1.0276x; 1.0276x over previous
//
#include <hip/hip_runtime.h>
#include <cstddef>
#include <cstdint>

namespace {
constexpr int kB   = 8;
constexpr int kT   = 2048;   // Tv == Ta
constexpr int kD   = 256;
constexpr int kK   = 8;      // num_neighbors (fixed by problem)
constexpr int kM   = kB * kT;
constexpr int kNCH = 64;     // s-chunks for gather partials
constexpr int kNC  = kB * kT;     // 16384 columns (b,s)
constexpr int kColCap = 64;       // bucket slots per column (mean load ~0.55)
constexpr int kOvCap  = 1 << 17;  // overflow list (normally empty)
constexpr int kStr = 264;         // LDS row stride in shorts (16B-aligned, ~2-way)
constexpr float kMinNormalF = 1.17549435e-38f;  // 2^-126: fp32 exp flush boundary
}

typedef __attribute__((ext_vector_type(8)))  __bf16 bf16x8;
typedef __attribute__((ext_vector_type(16))) float  f32x16;

__device__ inline unsigned short f2bf_rne(float x) {
  unsigned u = __float_as_uint(x);
  unsigned r = (u + 0x7FFFu + ((u >> 16) & 1u)) >> 16;
  return (unsigned short)r;
}
__device__ inline float bf2f(unsigned short h) {
  return __uint_as_float((unsigned)h << 16);
}
union FragU { uint4 u4; bf16x8 v; };

// ---- Kernel 0: WT[c][k] = bf16(W[k][c]), both weights via blockIdx.z -------
__global__ __launch_bounds__(256) void transposeW2(const float* __restrict__ W0,
                                                   const float* __restrict__ W1,
                                                   unsigned short* __restrict__ T0,
                                                   unsigned short* __restrict__ T1) {
  const float* W = blockIdx.z ? W1 : W0;
  unsigned short* WT = blockIdx.z ? T1 : T0;
  __shared__ float tile[32][33];
  const int k0 = blockIdx.y * 32, c0 = blockIdx.x * 32;
  const int tx = threadIdx.x & 31, ty = threadIdx.x >> 5;  // 32 x 8
#pragma unroll
  for (int i = 0; i < 4; ++i)
    tile[ty + i * 8][tx] = W[(size_t)(k0 + ty + i * 8) * kD + c0 + tx];
  __syncthreads();
#pragma unroll
  for (int i = 0; i < 4; ++i)
    WT[(size_t)(c0 + ty + i * 8) * kD + k0 + tx] = f2bf_rne(tile[tx][ty + i * 8]);
}

// ---- Kernel 1: Cb = bf16( bf16(X) @ WT^T ) + fused row norms ---------------
// A-in-registers: wave holds its 32-row X strip as 16 bf16 frags (64 VGPRs,
// statically indexed -- r6 lesson: dynamic/lambda staging spills). B (WT,
// 64 cols x K=256) staged to LDS ONCE per block -> zero K-loop barriers.
__global__ __launch_bounds__(256) void gemm_areg(const float* __restrict__ Xv,
                                                 const float* __restrict__ Xa,
                                                 const unsigned short* __restrict__ WvT,
                                                 const unsigned short* __restrict__ WaT,
                                                 unsigned short* __restrict__ Cv,
                                                 unsigned short* __restrict__ Ca,
                                                 float* __restrict__ nv,
                                                 float* __restrict__ na) {
  __shared__ unsigned short Ws[64 * kStr];
  const int z = blockIdx.z;
  const float* X = z ? Xa : Xv;
  const unsigned short* WT = z ? WaT : WvT;
  unsigned short* Cb = z ? Ca : Cv;
  float* nrm = z ? na : nv;
  const int r0 = blockIdx.x * 128;
  const int c0 = blockIdx.y * 64;
  const int tid = threadIdx.x;
  const int w = tid >> 6, lane = tid & 63;
  const int half = lane >> 5, ln = lane & 31;

  // stage WT cols c0..c0+63, all K (64 x 256 shorts)
#pragma unroll
  for (int i = 0; i < 8; ++i) {
    const int idx = i * 256 + tid;
    const int row = idx >> 5, g = idx & 31;
    const uint4 v = *reinterpret_cast<const uint4*>(WT + (size_t)(c0 + row) * kD + g * 8);
    *reinterpret_cast<uint4*>(Ws + row * kStr + g * 8) = v;
  }
  // A: lane's 32B k-slices of its row, cast fp32->bf16 into 16 frags
  const float* xrow = X + (size_t)(r0 + w * 32 + ln) * kD + half * 8;
  uint4 afr[16];
#pragma unroll
  for (int kc = 0; kc < 16; ++kc) {
    const float4 v0 = *reinterpret_cast<const float4*>(xrow + kc * 16);
    const float4 v1 = *reinterpret_cast<const float4*>(xrow + kc * 16 + 4);
    afr[kc].x = (unsigned)f2bf_rne(v0.x) | ((unsigned)f2bf_rne(v0.y) << 16);
    afr[kc].y = (unsigned)f2bf_rne(v0.z) | ((unsigned)f2bf_rne(v0.w) << 16);
    afr[kc].z = (unsigned)f2bf_rne(v1.x) | ((unsigned)f2bf_rne(v1.y) << 16);
    afr[kc].w = (unsigned)f2bf_rne(v1.z) | ((unsigned)f2bf_rne(v1.w) << 16);
  }
  f32x16 acc[2];
#pragma unroll
  for (int j = 0; j < 2; ++j)
#pragma unroll
    for (int i = 0; i < 16; ++i) acc[j][i] = 0.0f;
  __syncthreads();
#pragma unroll
  for (int kc = 0; kc < 16; ++kc) {
    FragU fa; fa.u4 = afr[kc];
#pragma unroll
    for (int cs = 0; cs < 2; ++cs) {
      FragU fb;
      fb.u4 = *reinterpret_cast<const uint4*>(Ws + (cs * 32 + ln) * kStr + kc * 16 + half * 8);
      acc[cs] = __builtin_amdgcn_mfma_f32_32x32x16_bf16(fa.v, fb.v, acc[cs], 0, 0, 0);
    }
  }
  // epilogue: store bf16 C; accumulate row norms of the ROUNDED values
  float ns[16];
#pragma unroll
  for (int r = 0; r < 16; ++r) ns[r] = 0.0f;
#pragma unroll
  for (int cs = 0; cs < 2; ++cs) {
    const int col = c0 + cs * 32 + ln;
#pragma unroll
    for (int r = 0; r < 16; ++r) {
      const int row = r0 + w * 32 + (r & 3) + 8 * (r >> 2) + 4 * half;
      const unsigned short us = f2bf_rne(acc[cs][r]);
      Cb[(size_t)row * kD + col] = us;
      const float f = bf2f(us);
      ns[r] += f * f;
    }
  }
#pragma unroll
  for (int r = 0; r < 16; ++r) {
    float v = ns[r];
#pragma unroll
    for (int off = 1; off < 32; off <<= 1) v += __shfl_xor(v, off, 64);
    if (ln == 0) {
      const int row = r0 + w * 32 + (r & 3) + 8 * (r >> 2) + 4 * half;
      atomicAdd(nrm + row, v);
    }
  }
}

// ---- Kernel 2a: distance keys, A(vm)-in-registers, s-sweep -----------------
// Block = 128 t-rows (4 waves x 32) x s-range 128. vm strip loaded once into
// 64 VGPRs/lane; per 64-wide s-tile: stage am full-K (33.8KB LDS) once, then
// 32 MFMA/wave between ONE barrier pair (r8 had 8 MFMA per pair + 4x the LDS
// traffic). Key semantics identical to rounds 1-8 (sq<7744 == dist<88 guard,
// flush below 2^-126).
__global__ __launch_bounds__(256) void keys_areg(const unsigned short* __restrict__ vmb,
                                                 const unsigned short* __restrict__ amb,
                                                 const float* __restrict__ vn2,
                                                 const float* __restrict__ an2,
                                                 unsigned* __restrict__ colCount,
                                                 uint2* __restrict__ colRecs,
                                                 unsigned* __restrict__ ovCount,
                                                 uint2* __restrict__ ovRecs) {
  __shared__ unsigned short amS[64 * kStr];
  const int b = blockIdx.z;
  const int t0 = blockIdx.x * 128;
  const int sr0 = blockIdx.y * 128;
  const int tid = threadIdx.x;
  const int w = tid >> 6, lane = tid & 63;
  const int half = lane >> 5, ln = lane & 31;

  // A: vm strip, 16 frags/lane (64 VGPRs), L2/L3-hot (vmb just written)
  const unsigned short* arow = vmb + ((size_t)b * kT + t0 + w * 32 + ln) * kD + half * 8;
  uint4 afr[16];
#pragma unroll
  for (int kc = 0; kc < 16; ++kc)
    afr[kc] = *reinterpret_cast<const uint4*>(arow + kc * 16);

  const float* v2p = vn2 + (size_t)b * kT + t0 + w * 32;

  for (int st = 0; st < 2; ++st) {          // two 64-wide s-tiles
    const int s0 = sr0 + st * 64;
    if (st) __syncthreads();                // LDS reuse guard
#pragma unroll
    for (int i = 0; i < 8; ++i) {           // stage am: 64 rows x 256 shorts
      const int idx = i * 256 + tid;
      const int row = idx >> 5, g = idx & 31;
      const uint4 v = *reinterpret_cast<const uint4*>(amb + ((size_t)b * kT + s0 + row) * kD + g * 8);
      *reinterpret_cast<uint4*>(amS + row * kStr + g * 8) = v;
    }
    f32x16 acc[2];
#pragma unroll
    for (int j = 0; j < 2; ++j)
#pragma unroll
      for (int i = 0; i < 16; ++i) acc[j][i] = 0.0f;
    __syncthreads();
#pragma unroll
    for (int kc = 0; kc < 16; ++kc) {
      FragU fa; fa.u4 = afr[kc];
#pragma unroll
      for (int ss = 0; ss < 2; ++ss) {
        FragU fb;
        fb.u4 = *reinterpret_cast<const uint4*>(amS + (ss * 32 + ln) * kStr + kc * 16 + half * 8);
        acc[ss] = __builtin_amdgcn_mfma_f32_32x32x16_bf16(fa.v, fb.v, acc[ss], 0, 0, 0);
      }
    }
    // epilogue: col(s)=lane&31, row(t)=(reg&3)+8*(reg>>2)+4*half
#pragma unroll
    for (int ss = 0; ss < 2; ++ss) {
      const int s = s0 + ss * 32 + ln;
      const float a2 = an2[(size_t)b * kT + s];
      const int c = (b << 11) | s;
#pragma unroll
      for (int g = 0; g < 4; ++g) {
        const float4 v2 = *reinterpret_cast<const float4*>(v2p + g * 8 + half * 4);
        const float v2a[4] = {v2.x, v2.y, v2.z, v2.w};
#pragma unroll
        for (int q = 0; q < 4; ++q) {
          const float raw = v2a[q] + a2 - 2.0f * acc[ss][4 * g + q];
          if (raw < 7744.0f) {  // == dist < 88; ~3e-4 of entries
            const float dist = sqrtf(fmaxf(raw, 0.0f));
            const float e = expf(-dist);
            if (e >= kMinNormalF) {
              const int t = t0 + w * 32 + g * 8 + half * 4 + q;
              const unsigned slot = atomicAdd(&colCount[c], 1u);
              if (slot < (unsigned)kColCap) {
                colRecs[(size_t)c * kColCap + slot] = make_uint2(__float_as_uint(e), (unsigned)t);
              } else {
                const unsigned pos = ((unsigned)b << 22) | ((unsigned)s << 11) | (unsigned)t;
                const unsigned oi = atomicAdd(ovCount, 1u);
                if (oi < (unsigned)kOvCap) ovRecs[oi] = make_uint2(__float_as_uint(e), pos);
              }
            }
          }
        }
      }
    }
  }
}

// ---- Kernel 2b: per-column top-8 from its own bucket -----------------------
// Writes idxT[(b*kK + r)*kT + s] (gather-friendly layout).
__global__ __launch_bounds__(256) void finalize_topk(const unsigned* __restrict__ colCount,
                                                     const uint2* __restrict__ colRecs,
                                                     const unsigned* __restrict__ ovCount,
                                                     const uint2* __restrict__ ovRecs,
                                                     int* __restrict__ idxT) {
  const int c = blockIdx.x * 256 + threadIdx.x;  // (b<<11)|s
  unsigned K[8];
  int T[8];
#pragma unroll
  for (int i = 0; i < 8; ++i) { K[i] = 0u; T[i] = 0x7FFFFFFF; }
  const int cnt = (int)colCount[c];
  const int m = min(cnt, kColCap);
  for (int i = 0; i < m; ++i) {
    const uint2 r = colRecs[(size_t)c * kColCap + i];
    const unsigned kx = r.x;
    const int tx = (int)r.y;
    if (kx > K[7] || (kx == K[7] && tx < T[7])) {
      K[7] = kx; T[7] = tx;
#pragma unroll
      for (int q = 7; q >= 1; --q) {
        const bool sw = (K[q] > K[q - 1]) || (K[q] == K[q - 1] && T[q] < T[q - 1]);
        if (sw) {
          const unsigned tk = K[q]; K[q] = K[q - 1]; K[q - 1] = tk;
          const int tt = T[q];      T[q] = T[q - 1]; T[q - 1] = tt;
        }
      }
    }
  }
  if (cnt > kColCap) {  // correctness fallback; normally never taken
    int n = (int)*ovCount;
    if (n > kOvCap) n = kOvCap;
    for (int i = 0; i < n; ++i) {
      const uint2 r = ovRecs[i];
      if ((int)(r.y >> 11) == c) {
        const unsigned kx = r.x;
        const int tx = (int)(r.y & 2047u);
        if (kx > K[7] || (kx == K[7] && tx < T[7])) {
          K[7] = kx; T[7] = tx;
#pragma unroll
          for (int q = 7; q >= 1; --q) {
            const bool sw = (K[q] > K[q - 1]) || (K[q] == K[q - 1] && T[q] < T[q - 1]);
            if (sw) {
              const unsigned tk = K[q]; K[q] = K[q - 1]; K[q - 1] = tk;
              const int tt = T[q];      T[q] = T[q - 1]; T[q - 1] = tt;
            }
          }
        }
      }
    }
  }
  int mcnt = 0;
#pragma unroll
  for (int i = 0; i < 8; ++i) if (K[i] > 0u) mcnt++;
  int outv[8];
#pragma unroll
  for (int i = 0; i < 8; ++i) outv[i] = T[i];
  int cand = 0;
  for (int r = mcnt; r < 8; ++r) {
    bool taken = true;
    while (taken) {
      taken = false;
#pragma unroll
      for (int q = 0; q < 8; ++q)
        if (q < mcnt && T[q] == cand) taken = true;
      if (taken) cand++;
    }
    outv[r] = cand++;
  }
  const int b = c >> 11, s = c & 2047;
#pragma unroll
  for (int r = 0; r < 8; ++r) idxT[((size_t)b * kK + r) * kT + s] = outv[r];
}

// ---- Kernel 3: partial gather-sums (r7 form: no atomics on out) ------------
__global__ __launch_bounds__(256) void gather_kernel(const float* __restrict__ visual,
                                                     const float* __restrict__ audio,
                                                     const int* __restrict__ idxT,
                                                     float* __restrict__ pv,
                                                     float* __restrict__ pa) {
  const int blk = blockIdx.x;        // bj * kNCH + ch
  const int ch = blk & (kNCH - 1);
  const int bj = blk / kNCH;         // b*8 + j
  const int b = bj >> 3;
  const int d = threadIdx.x;
  const int* ip = idxT + (size_t)bj * kT + ch * (kT / kNCH);
  float accV = 0.f, accA = 0.f;
  for (int g = 0; g < kT / kNCH / 4; ++g) {
    const int4 cur = *reinterpret_cast<const int4*>(ip + g * 4);
    const int ts[4] = {cur.x, cur.y, cur.z, cur.w};
#pragma unroll
    for (int u = 0; u < 4; ++u) {
      const size_t base = ((size_t)b * kT + ts[u]) * kD + d;
      accV += visual[base];
      accA += audio[base];
    }
  }
  pv[(size_t)blk * kD + d] = accV;
  pa[(size_t)blk * kD + d] = accA;
}

// ---- Kernel 4: reduce partials, divide by Ta, write both outputs -----------
__global__ __launch_bounds__(256) void reduce_kernel(const float* __restrict__ pv,
                                                     const float* __restrict__ pa,
                                                     float* __restrict__ out) {
  const int bj = blockIdx.x;
  const int d = threadIdx.x;
  float sV = 0.f, sA = 0.f;
#pragma unroll 8
  for (int ch = 0; ch < kNCH; ++ch) {
    sV += pv[((size_t)bj * kNCH + ch) * kD + d];
    sA += pa[((size_t)bj * kNCH + ch) * kD + d];
  }
  out[(size_t)bj * kD + d] = sV * (1.0f / kT);
  out[(size_t)kB * kK * kD + (size_t)bj * kD + d] = sA * (1.0f / kT);
}

extern "C" void kernel_launch(void* const* d_in, const int* in_sizes, int n_in,
                              void* d_out, int out_size, void* d_ws, size_t ws_size,
                              hipStream_t stream) {
  (void)in_sizes; (void)n_in; (void)out_size; (void)ws_size;
  const float* visual = (const float*)d_in[0];
  const float* audio  = (const float*)d_in[1];
  const float* Wv     = (const float*)d_in[2];
  const float* Wa     = (const float*)d_in[3];
  float* out = (float*)d_out;

  // workspace layout (~35 MB). [vn2|an2|colCount|ovCount] contiguous: 1 memset.
  char* ws = (char*)d_ws;
  unsigned short* WvT = (unsigned short*)ws;                // kD*kD bf16 128KB
  unsigned short* WaT = WvT + (size_t)kD * kD;
  unsigned short* vmb = WaT + (size_t)kD * kD;              // kM*kD bf16  8MB
  unsigned short* amb = vmb + (size_t)kM * kD;              // 8MB
  float* vn2 = (float*)(amb + (size_t)kM * kD);             // kM f32 (memset)
  float* an2 = vn2 + kM;                                    // kM f32 (memset)
  unsigned* colCount = (unsigned*)(an2 + kM);               // kNC u32 (memset)
  unsigned* ovCount  = colCount + kNC;                      // 1 u32 +3 pad (memset)
  uint2* colRecs = (uint2*)(ovCount + 4);                   // kNC*kColCap uint2 8MB
  uint2* ovRecs  = colRecs + (size_t)kNC * kColCap;         // kOvCap uint2 1MB
  int* idxT = (int*)(ovRecs + kOvCap);                      // kB*kK*kT i32 512KB
  float* pv = (float*)(idxT + (size_t)kB * kK * kT);        // 4MB
  float* pa = pv + (size_t)kB * kK * kNCH * kD;             // 4MB

  hipMemsetAsync(vn2, 0, (size_t)(2 * kM + kNC + 4) * sizeof(float), stream);
  transposeW2<<<dim3(kD / 32, kD / 32, 2), 256, 0, stream>>>(Wv, Wa, WvT, WaT);
  gemm_areg<<<dim3(kM / 128, kD / 64, 2), 256, 0, stream>>>(visual, audio, WvT, WaT,
                                                            vmb, amb, vn2, an2);
  keys_areg<<<dim3(kT / 128, kT / 128, kB), 256, 0, stream>>>(vmb, amb, vn2, an2,
                                                              colCount, colRecs, ovCount, ovRecs);
  finalize_topk<<<dim3(kNC / 256), 256, 0, stream>>>(colCount, colRecs, ovCount, ovRecs, idxT);
  gather_kernel<<<dim3(kB * kK * kNCH), 256, 0, stream>>>(visual, audio, idxT, pv, pa);
  reduce_kernel<<<dim3(kB * kK), 256, 0, stream>>>(pv, pa, out);
}